// Round 11
// baseline (166.765 us; speedup 1.0000x reference)
//
#include <hip/hip_runtime.h>
#include <cstdint>
#include <cstddef>

typedef __bf16 bf16_t;
typedef __bf16 bf16x8 __attribute__((ext_vector_type(8)));
typedef __bf16 bf16x4 __attribute__((ext_vector_type(4)));
typedef float f32x4 __attribute__((ext_vector_type(4)));

#define N_SEQ 2048
#define BATCH 2
#define EMB   1024
#define HID   1024
#define NHEAD 16
#define HDIM  64
#define NBROW (N_SEQ * BATCH)   /* 4096 GEMM rows (n*B+b) */
#define ATT_SCALE2 (0.03125f * 1.44269504f)  /* 1/sqrt(1024) * log2(e) */

#define EXP2F(x) __builtin_amdgcn_exp2f(x)   /* __exp2f collides with glibc macro */

static __device__ __forceinline__ void async_copy16(const bf16_t* g, bf16_t* l) {
  __builtin_amdgcn_global_load_lds((const __attribute__((address_space(1))) void*)g,
                                   (__attribute__((address_space(3))) void*)l,
                                   16, 0, 0);
}

// ---------------- fused prep: convert x + transpose both weights -----------
__global__ __launch_bounds__(256) void prep_kernel(
    const float* __restrict__ x, const float* __restrict__ Wp,
    const float* __restrict__ Wo, bf16_t* __restrict__ Xb,
    bf16_t* __restrict__ Wpt, bf16_t* __restrict__ Wot) {
  int bid = blockIdx.x;
  if (bid < 4096) {
    int i = (bid * 256 + threadIdx.x) * 4;
    float4 v = *(const float4*)(x + i);
    bf16x4 o;
    o[0] = (bf16_t)v.x; o[1] = (bf16_t)v.y; o[2] = (bf16_t)v.z; o[3] = (bf16_t)v.w;
    *(bf16x4*)(Xb + i) = o;
    return;
  }
  __shared__ float tile[32][33];
  const float* in; bf16_t* out; int R, C, bx;
  if (bid < 4096 + 3072) { bx = bid - 4096; in = Wp; out = Wpt; R = 1024; C = 3072; }
  else                   { bx = bid - 7168; in = Wo; out = Wot; R = 1024; C = 1024; }
  int gx = C / 32;
  int bc = (bx % gx) * 32, br = (bx / gx) * 32;
  int tx = threadIdx.x & 31, ty = threadIdx.x >> 5;   // 32 x 8
  #pragma unroll
  for (int i = 0; i < 32; i += 8)
    tile[ty + i][tx] = in[(size_t)(br + ty + i) * C + bc + tx];
  __syncthreads();
  #pragma unroll
  for (int i = 0; i < 32; i += 8)
    out[(size_t)(bc + ty + i) * R + br + tx] = (bf16_t)tile[tx][ty + i];
}

// ---------------- pipelined GEMM: C = A * Bt^T + bias ----------------------
// R1-verified structure: one barrier per K-iter, double-buffered
// global_load_lds, 0-conflict XOR swizzle. BN=192 (QKV): grid 32x16 = 512
// blocks = exactly 2 blocks/CU (80KB LDS) -> one scheduling round, and
// MFMA:ds_read per kk = 24:10 (was 16:6). V^T emission is per-head (the K/V
// boundary at col 2048 falls inside a block, always at a 64-col head edge).
template <int BM, int BN, bool OUT_BF16, bool SCALEQ, bool WRITE_VT>
__global__ __launch_bounds__(256) void gemm_bt_kernel(
    const bf16_t* __restrict__ A, const bf16_t* __restrict__ Bt,
    const float* __restrict__ bias, void* __restrict__ Cout,
    bf16_t* __restrict__ Vt, int M, int Nn, int K) {
  constexpr int BK = 64;
  constexpr int MT = BM / 32;
  constexpr int NT = BN / 32;
  constexpr int CA = BM / 32;              // A 16B-chunks per thread
  constexpr int CB = BN / 32;              // B 16B-chunks per thread
  constexpr int ASZ = BM * BK;             // elems per A buffer
  constexpr int BSZ = BN * BK;             // elems per B buffer
  constexpr int NHT = BN / 64;             // heads per tile (V epilogue)
  __shared__ __align__(16) bf16_t smem[2 * ASZ + 2 * BSZ];
  bf16_t* const Asb = smem;
  bf16_t* const Bsb = smem + 2 * ASZ;
  int tid = threadIdx.x;
  int wave = tid >> 6, lane = tid & 63;
  int c = lane & 15, quad = lane >> 4;
  int bm = blockIdx.x * BM;
  int bn = blockIdx.y * BN;
  int wm = (wave & 1) * (BM / 2), wn = (wave >> 1) * (BN / 2);
  f32x4 acc[MT][NT] = {};

  const bf16_t* agp[CA]; int alo[CA];
  const bf16_t* bgp[CB]; int blo[CB];
  #pragma unroll
  for (int i = 0; i < CA; ++i) {
    int p = i * 256 + tid;
    int row = p >> 3, ko = (p & 7) ^ (row & 7);
    agp[i] = A + (size_t)(bm + row) * K + ko * 8;
    alo[i] = (i * 256 + wave * 64) * 8;
  }
  #pragma unroll
  for (int i = 0; i < CB; ++i) {
    int p = i * 256 + tid;
    int row = p >> 3, ko = (p & 7) ^ (row & 7);
    bgp[i] = Bt + (size_t)(bn + row) * K + ko * 8;
    blo[i] = (i * 256 + wave * 64) * 8;
  }

  #pragma unroll
  for (int i = 0; i < CA; ++i) async_copy16(agp[i], Asb + alo[i]);
  #pragma unroll
  for (int i = 0; i < CB; ++i) async_copy16(bgp[i], Bsb + blo[i]);

  int nkb = K / BK;
  for (int ki = 0; ki < nkb; ++ki) {
    __syncthreads();   // drains tile-ki loads (issued one compute phase ago)
    if (ki + 1 < nkb) {
      int kb = (ki + 1) * BK;
      bf16_t* an = Asb + ((ki + 1) & 1) * ASZ;
      bf16_t* bnx = Bsb + ((ki + 1) & 1) * BSZ;
      #pragma unroll
      for (int i = 0; i < CA; ++i) async_copy16(agp[i] + kb, an + alo[i]);
      #pragma unroll
      for (int i = 0; i < CB; ++i) async_copy16(bgp[i] + kb, bnx + blo[i]);
    }
    const bf16_t* as = Asb + (ki & 1) * ASZ;
    const bf16_t* bs = Bsb + (ki & 1) * BSZ;
    #pragma unroll
    for (int kk = 0; kk < 2; ++kk) {
      bf16x8 af[MT], bf[NT];
      #pragma unroll
      for (int mt = 0; mt < MT; ++mt) {
        int row = wm + mt * 16 + c;
        int slot = (kk * 4 + quad) ^ (row & 7);
        af[mt] = *(const bf16x8*)(as + (size_t)(row * 8 + slot) * 8);
      }
      #pragma unroll
      for (int nt = 0; nt < NT; ++nt) {
        int row = wn + nt * 16 + c;
        int slot = (kk * 4 + quad) ^ (row & 7);
        bf[nt] = *(const bf16x8*)(bs + (size_t)(row * 8 + slot) * 8);
      }
      #pragma unroll
      for (int mt = 0; mt < MT; ++mt)
        #pragma unroll
        for (int nt = 0; nt < NT; ++nt)
          acc[mt][nt] = __builtin_amdgcn_mfma_f32_16x16x32_bf16(
              af[mt], bf[nt], acc[mt][nt], 0, 0, 0);
    }
  }

  // any V columns in this tile?
  bool do_vt = WRITE_VT && (bn + BN > 2 * HID);
  bf16_t* tb = smem;             // reuse staging LDS: NHT*2*4608 elems <= smem
  if (do_vt) __syncthreads();    // last tile's ds_reads done before smem reuse

  #pragma unroll
  for (int nt = 0; nt < NT; ++nt) {
    int col = bn + wn + nt * 16 + c;
    float bv = bias[col];
    float sc = (SCALEQ && col < HID) ? ATT_SCALE2 : 1.0f;
    bool vt_el = do_vt && (col >= 2 * HID);   // uniform per (nt): 16-col group
    #pragma unroll
    for (int mt = 0; mt < MT; ++mt) {
      #pragma unroll
      for (int r = 0; r < 4; ++r) {
        int loc = wm + mt * 16 + quad * 4 + r;        // row within tile
        int row = bm + loc;                           // C layout: row=(lane>>4)*4+reg
        float v = (acc[mt][nt][r] + bv) * sc;
        if (OUT_BF16)
          ((bf16_t*)Cout)[(size_t)row * Nn + col] = (bf16_t)v;
        else
          ((float*)Cout)[(size_t)row * Nn + col] = v;
        if (vt_el) {
          int dg = wn + nt * 16 + c;                  // col within tile [0,BN)
          int hh = dg >> 6, dl = dg & 63;             // head-in-tile, d in head
          tb[((loc & 1) * NHT + hh) * 4608 + dl * 72 + (loc >> 1)] = (bf16_t)v;
        }
      }
    }
  }

  if (do_vt) {
    __syncthreads();
    int n2 = (tid & 7) * 8;
    #pragma unroll
    for (int i = 0; i < 2; ++i) {        // batch b
      #pragma unroll
      for (int hh = 0; hh < NHT; ++hh) { // head within tile
        int gcol = bn + hh * 64;
        if (gcol >= 2 * HID) {
          int h = (gcol - 2 * HID) >> 6;
          #pragma unroll
          for (int k = 0; k < 2; ++k) {
            int d = (tid >> 3) + k * 32;
            bf16x8 vv = *(const bf16x8*)(tb + ((i * NHT + hh) * 4608) + d * 72 + n2);
            *(bf16x8*)(Vt + (size_t)((i * 16 + h) * HDIM + d) * N_SEQ + bm / 2 + n2) = vv;
          }
        }
      }
    }
  }
}

// ---------------- flash attention: T15 two-tile pipeline (R9-verified) -----
__global__ __launch_bounds__(512, 4) void flash_attn_kernel(
    const bf16_t* __restrict__ Pj, const bf16_t* __restrict__ Vt,
    bf16_t* __restrict__ AO) {
  __shared__ __align__(16) bf16_t Ks[3][64 * 64];   // [j][d] swizzled
  __shared__ __align__(16) bf16_t Vs[3][64 * 64];   // [d][j] swizzled
  __shared__ __align__(16) bf16_t Ps[8][16 * 64];   // per-wave P[i][j] swizzled
  const int PJP = 3 * HID;
  int tid = threadIdx.x, wave = tid >> 6, lane = tid & 63;
  int c = lane & 15, quad = lane >> 4;
  int c7 = c & 7;
  int bid = blockIdx.x;
  int qb = (bid < 256) ? (15 - (bid >> 5)) : ((bid - 256) >> 5);
  int bh = bid & 31;
  int h = bh & 15, b = bh >> 4;
  int i0 = qb * 128;

  int i_row = i0 + wave * 16 + c;
  const bf16_t* qg = Pj + (size_t)(i_row * BATCH + b) * PJP + h * HDIM + quad * 8;
  bf16x8 qf0 = *(const bf16x8*)(qg);
  bf16x8 qf1 = *(const bf16x8*)(qg + 32);

  f32x4 o[4] = {};                   // O^T: rows d, col i=c
  float lrow = 0.f;

  int jr = tid >> 3, oc = tid & 7;
  int lds_off = jr * 64 + (oc ^ (jr & 7)) * 8;
  const bf16_t* kg0 = Pj + (size_t)b * PJP + HID + h * HDIM + oc * 8;
  const bf16_t* vg0 = Vt + (size_t)(bh * HDIM + jr) * N_SEQ + oc * 8;

  int njt = 2 * qb + 2;              // always >= 2

  // ---- prologue: stage tiles 0,1; QK(0); prefetch tile 2 ----
  bf16x8 kreg = *(const bf16x8*)(kg0 + (size_t)jr * BATCH * PJP);
  bf16x8 vreg = *(const bf16x8*)(vg0);
  *(bf16x8*)(Ks[0] + lds_off) = kreg;
  *(bf16x8*)(Vs[0] + lds_off) = vreg;
  kreg = *(const bf16x8*)(kg0 + (size_t)(64 + jr) * BATCH * PJP);
  vreg = *(const bf16x8*)(vg0 + 64);
  *(bf16x8*)(Ks[1] + lds_off) = kreg;
  *(bf16x8*)(Vs[1] + lds_off) = vreg;
  __syncthreads();                   // publish buffers 0 and 1

  f32x4 st[4];
  #pragma unroll
  for (int mt = 0; mt < 4; ++mt) {
    const bf16_t* kr = Ks[0] + (mt * 16 + c) * 64;
    bf16x8 ka0 = *(const bf16x8*)(kr + ((quad) ^ c7) * 8);
    bf16x8 ka1 = *(const bf16x8*)(kr + ((quad + 4) ^ c7) * 8);
    f32x4 s = {};
    s = __builtin_amdgcn_mfma_f32_16x16x32_bf16(ka0, qf0, s, 0, 0, 0);
    st[mt] = __builtin_amdgcn_mfma_f32_16x16x32_bf16(ka1, qf1, s, 0, 0, 0);
  }
  if (njt > 2) {
    kreg = *(const bf16x8*)(kg0 + (size_t)(128 + jr) * BATCH * PJP);
    vreg = *(const bf16x8*)(vg0 + 128);
  }

  for (int jt = 0; jt < njt; ++jt) {
    if (jt) __syncthreads();         // publish buf[(jt+1)%3]; WAR-guard buf[(jt+2)%3]
    if (jt + 2 < njt) {              // write tile jt+2 (regs loaded one iter ago)
      *(bf16x8*)(Ks[(jt + 2) % 3] + lds_off) = kreg;
      *(bf16x8*)(Vs[(jt + 2) % 3] + lds_off) = vreg;
    }
    if (jt + 3 < njt) {              // prefetch tile jt+3 into regs
      int j0n = (jt + 3) * 64;
      kreg = *(const bf16x8*)(kg0 + (size_t)(j0n + jr) * BATCH * PJP);
      vreg = *(const bf16x8*)(vg0 + j0n);
    }

    // QK(jt+1) issued BEFORE the exp of tile jt (independent -> interleave)
    f32x4 stN[4];
    bool more = (jt + 1 < njt);
    if (more) {
      const bf16_t* ks = Ks[(jt + 1) % 3];
      #pragma unroll
      for (int mt = 0; mt < 4; ++mt) {
        const bf16_t* kr = ks + (mt * 16 + c) * 64;
        bf16x8 ka0 = *(const bf16x8*)(kr + ((quad) ^ c7) * 8);
        bf16x8 ka1 = *(const bf16x8*)(kr + ((quad + 4) ^ c7) * 8);
        f32x4 s = {};
        s = __builtin_amdgcn_mfma_f32_16x16x32_bf16(ka0, qf0, s, 0, 0, 0);
        stN[mt] = __builtin_amdgcn_mfma_f32_16x16x32_bf16(ka1, qf1, s, 0, 0, 0);
      }
    }

    // ---- softmax finish of tile jt (VALU, overlaps QK above) ----
    if (jt >= 2 * qb) {
      int j0 = jt * 64;
      int ig = i0 + wave * 16 + c;
      #pragma unroll
      for (int mt = 0; mt < 4; ++mt)
        #pragma unroll
        for (int r = 0; r < 4; ++r)
          if (j0 + mt * 16 + quad * 4 + r > ig) st[mt][r] = -1e30f;
    }
    #pragma unroll
    for (int mt = 0; mt < 4; ++mt)
      #pragma unroll
      for (int r = 0; r < 4; ++r) {
        st[mt][r] = EXP2F(st[mt][r]);
        lrow += st[mt][r];
      }

    bf16_t* pw = Ps[wave];
    #pragma unroll
    for (int mt = 0; mt < 4; ++mt) {
      bf16x4 pv;
      #pragma unroll
      for (int r = 0; r < 4; ++r) pv[r] = (bf16_t)st[mt][r];
      int joct = mt * 2 + (quad >> 1);
      *(bf16x4*)(pw + c * 64 + (joct ^ c7) * 8 + (quad & 1) * 4) = pv;
    }
    const bf16_t* pr = pw + c * 64;
    bf16x8 pa0 = *(const bf16x8*)(pr + ((quad) ^ c7) * 8);
    bf16x8 pa1 = *(const bf16x8*)(pr + ((quad + 4) ^ c7) * 8);

    const bf16_t* vs = Vs[jt % 3];
    #pragma unroll
    for (int nt = 0; nt < 4; ++nt) {
      const bf16_t* vr = vs + (nt * 16 + c) * 64;
      bf16x8 vb0 = *(const bf16x8*)(vr + ((quad) ^ c7) * 8);
      bf16x8 vb1 = *(const bf16x8*)(vr + ((quad + 4) ^ c7) * 8);
      o[nt] = __builtin_amdgcn_mfma_f32_16x16x32_bf16(vb0, pa0, o[nt], 0, 0, 0);
      o[nt] = __builtin_amdgcn_mfma_f32_16x16x32_bf16(vb1, pa1, o[nt], 0, 0, 0);
    }

    if (more) {
      #pragma unroll
      for (int mt = 0; mt < 4; ++mt) st[mt] = stN[mt];
    }
  }

  float lfull = lrow;
  lfull += __shfl_xor(lfull, 16);
  lfull += __shfl_xor(lfull, 32);
  float linv = 1.0f / lfull;
  int orow = (i0 + wave * 16 + c) * BATCH + b;
  #pragma unroll
  for (int nt = 0; nt < 4; ++nt) {
    bf16x4 pv;
    #pragma unroll
    for (int r = 0; r < 4; ++r) pv[r] = (bf16_t)(o[nt][r] * linv);
    *(bf16x4*)(AO + (size_t)orow * HID + h * HDIM + nt * 16 + quad * 4) = pv;
  }
}

extern "C" void kernel_launch(void* const* d_in, const int* in_sizes, int n_in,
                              void* d_out, int out_size, void* d_ws, size_t ws_size,
                              hipStream_t stream) {
  const float* x      = (const float*)d_in[0];   // [2048][2][1024]
  const float* W_proj = (const float*)d_in[1];   // [1024][3072]
  const float* b_proj = (const float*)d_in[2];   // [3072]
  const float* W_out  = (const float*)d_in[3];   // [1024][1024]
  const float* b_out  = (const float*)d_in[4];   // [1024]

  bf16_t* Xb  = (bf16_t*)d_ws;                               // 4096*1024
  bf16_t* Wpt = Xb  + (size_t)NBROW * EMB;                   // 3072*1024
  bf16_t* Wot = Wpt + (size_t)3 * HID * EMB;                 // 1024*1024
  bf16_t* Pj  = Wot + (size_t)HID * EMB;                     // 4096*3072
  bf16_t* AO  = Pj  + (size_t)NBROW * 3 * HID;               // 4096*1024
  bf16_t* Vt  = AO  + (size_t)NBROW * HID;                   // 32*64*2048

  prep_kernel<<<8192, 256, 0, stream>>>(x, W_proj, W_out, Xb, Wpt, Wot);
  // QKV: BN=192 -> 512 blocks = exactly 2/CU, one scheduling round
  gemm_bt_kernel<128, 192, true, true, true>
      <<<dim3(NBROW / 128, 3 * HID / 192), 256, 0, stream>>>(
      Xb, Wpt, b_proj, (void*)Pj, Vt, NBROW, 3 * HID, EMB);
  flash_attn_kernel<<<512, 512, 0, stream>>>(Pj, Vt, AO);
  // out-projection: BN=64 -> 512 blocks (R10-verified)
  gemm_bt_kernel<128, 64, false, false, false>
      <<<dim3(NBROW / 128, EMB / 64), 256, 0, stream>>>(
      AO, Wot, b_out, d_out, nullptr, NBROW, EMB, HID);
}

// Round 12
// 157.295 us; speedup vs baseline: 1.0602x; 1.0602x over previous
//
#include <hip/hip_runtime.h>
#include <cstdint>
#include <cstddef>

typedef __bf16 bf16_t;
typedef __bf16 bf16x8 __attribute__((ext_vector_type(8)));
typedef __bf16 bf16x4 __attribute__((ext_vector_type(4)));
typedef float f32x4 __attribute__((ext_vector_type(4)));

#define N_SEQ 2048
#define BATCH 2
#define EMB   1024
#define HID   1024
#define NHEAD 16
#define HDIM  64
#define NBROW (N_SEQ * BATCH)   /* 4096 GEMM rows (n*B+b) */
#define ATT_SCALE2 (0.03125f * 1.44269504f)  /* 1/sqrt(1024) * log2(e) */

#define EXP2F(x) __builtin_amdgcn_exp2f(x)   /* __exp2f collides with glibc macro */

static __device__ __forceinline__ void async_copy16(const bf16_t* g, bf16_t* l) {
  __builtin_amdgcn_global_load_lds((const __attribute__((address_space(1))) void*)g,
                                   (__attribute__((address_space(3))) void*)l,
                                   16, 0, 0);
}

// ---------------- fused prep: convert x + transpose both weights -----------
__global__ __launch_bounds__(256) void prep_kernel(
    const float* __restrict__ x, const float* __restrict__ Wp,
    const float* __restrict__ Wo, bf16_t* __restrict__ Xb,
    bf16_t* __restrict__ Wpt, bf16_t* __restrict__ Wot) {
  int bid = blockIdx.x;
  if (bid < 4096) {
    int i = (bid * 256 + threadIdx.x) * 4;
    float4 v = *(const float4*)(x + i);
    bf16x4 o;
    o[0] = (bf16_t)v.x; o[1] = (bf16_t)v.y; o[2] = (bf16_t)v.z; o[3] = (bf16_t)v.w;
    *(bf16x4*)(Xb + i) = o;
    return;
  }
  __shared__ float tile[32][33];
  const float* in; bf16_t* out; int R, C, bx;
  if (bid < 4096 + 3072) { bx = bid - 4096; in = Wp; out = Wpt; R = 1024; C = 3072; }
  else                   { bx = bid - 7168; in = Wo; out = Wot; R = 1024; C = 1024; }
  int gx = C / 32;
  int bc = (bx % gx) * 32, br = (bx / gx) * 32;
  int tx = threadIdx.x & 31, ty = threadIdx.x >> 5;   // 32 x 8
  #pragma unroll
  for (int i = 0; i < 32; i += 8)
    tile[ty + i][tx] = in[(size_t)(br + ty + i) * C + bc + tx];
  __syncthreads();
  #pragma unroll
  for (int i = 0; i < 32; i += 8)
    out[(size_t)(bc + ty + i) * R + br + tx] = (bf16_t)tile[tx][ty + i];
}

// ---------------- pipelined GEMM: C = A * Bt^T + bias ----------------------
// R1-verified structure: one barrier per K-iter, double-buffered
// global_load_lds, 0-conflict XOR swizzle. TPB param sets wave count:
//   TPB=256: 4 waves (2x2), 64x64 per wave  (out-GEMM, R10-verified config)
//   TPB=512: 8 waves (2x4), 64x32 per wave  (QKV: 16 waves/CU at 2 blk/CU
//            to hide the vmcnt-drain; tail round runs at 8 waves/CU)
template <int BM, int BN, int TPB, bool OUT_BF16, bool SCALEQ, bool WRITE_VT>
__global__ __launch_bounds__(TPB) void gemm_bt_kernel(
    const bf16_t* __restrict__ A, const bf16_t* __restrict__ Bt,
    const float* __restrict__ bias, void* __restrict__ Cout,
    bf16_t* __restrict__ Vt, int M, int Nn, int K) {
  constexpr int BK = 64;
  constexpr int NW = TPB / 64;             // waves per block
  constexpr int WROW = 2, WCOL = NW / 2;   // wave grid
  constexpr int MT = BM / WROW / 16;
  constexpr int NT = BN / WCOL / 16;
  constexpr int CA = BM * 8 / TPB;         // A 16B-chunks per thread
  constexpr int CB = BN * 8 / TPB;         // B 16B-chunks per thread
  constexpr int ASZ = BM * BK;             // elems per A buffer
  constexpr int BSZ = BN * BK;             // elems per B buffer
  __shared__ __align__(16) bf16_t smem[2 * ASZ + 2 * BSZ];
  bf16_t* const Asb = smem;
  bf16_t* const Bsb = smem + 2 * ASZ;
  int tid = threadIdx.x;
  int wave = tid >> 6, lane = tid & 63;
  int c = lane & 15, quad = lane >> 4;
  int bm = blockIdx.x * BM;
  int bn = blockIdx.y * BN;
  int wm = (wave % WROW) * (BM / WROW);
  int wn = (wave / WROW) * (BN / WCOL);
  f32x4 acc[MT][NT] = {};

  const bf16_t* agp[CA]; int alo[CA];
  const bf16_t* bgp[CB]; int blo[CB];
  #pragma unroll
  for (int i = 0; i < CA; ++i) {
    int p = i * TPB + tid;
    int row = p >> 3, ko = (p & 7) ^ (row & 7);
    agp[i] = A + (size_t)(bm + row) * K + ko * 8;
    alo[i] = (i * TPB + wave * 64) * 8;
  }
  #pragma unroll
  for (int i = 0; i < CB; ++i) {
    int p = i * TPB + tid;
    int row = p >> 3, ko = (p & 7) ^ (row & 7);
    bgp[i] = Bt + (size_t)(bn + row) * K + ko * 8;
    blo[i] = (i * TPB + wave * 64) * 8;
  }

  #pragma unroll
  for (int i = 0; i < CA; ++i) async_copy16(agp[i], Asb + alo[i]);
  #pragma unroll
  for (int i = 0; i < CB; ++i) async_copy16(bgp[i], Bsb + blo[i]);

  int nkb = K / BK;
  for (int ki = 0; ki < nkb; ++ki) {
    __syncthreads();   // drains tile-ki loads (issued one compute phase ago)
    if (ki + 1 < nkb) {
      int kb = (ki + 1) * BK;
      bf16_t* an = Asb + ((ki + 1) & 1) * ASZ;
      bf16_t* bnx = Bsb + ((ki + 1) & 1) * BSZ;
      #pragma unroll
      for (int i = 0; i < CA; ++i) async_copy16(agp[i] + kb, an + alo[i]);
      #pragma unroll
      for (int i = 0; i < CB; ++i) async_copy16(bgp[i] + kb, bnx + blo[i]);
    }
    const bf16_t* as = Asb + (ki & 1) * ASZ;
    const bf16_t* bs = Bsb + (ki & 1) * BSZ;
    #pragma unroll
    for (int kk = 0; kk < 2; ++kk) {
      bf16x8 af[MT], bf[NT];
      #pragma unroll
      for (int mt = 0; mt < MT; ++mt) {
        int row = wm + mt * 16 + c;
        int slot = (kk * 4 + quad) ^ (row & 7);
        af[mt] = *(const bf16x8*)(as + (size_t)(row * 8 + slot) * 8);
      }
      #pragma unroll
      for (int nt = 0; nt < NT; ++nt) {
        int row = wn + nt * 16 + c;
        int slot = (kk * 4 + quad) ^ (row & 7);
        bf[nt] = *(const bf16x8*)(bs + (size_t)(row * 8 + slot) * 8);
      }
      #pragma unroll
      for (int mt = 0; mt < MT; ++mt)
        #pragma unroll
        for (int nt = 0; nt < NT; ++nt)
          acc[mt][nt] = __builtin_amdgcn_mfma_f32_16x16x32_bf16(
              af[mt], bf[nt], acc[mt][nt], 0, 0, 0);
    }
  }

  bool do_vt = WRITE_VT && (bn >= 2 * HID);
  bf16_t* tb = smem;             // reuse staging LDS for V^T: 2heads*2b*4608*2B=36KB
  if (do_vt) __syncthreads();    // last tile's ds_reads done before smem reuse

  #pragma unroll
  for (int nt = 0; nt < NT; ++nt) {
    int col = bn + wn + nt * 16 + c;
    float bv = bias[col];
    float sc = (SCALEQ && col < HID) ? ATT_SCALE2 : 1.0f;
    #pragma unroll
    for (int mt = 0; mt < MT; ++mt) {
      #pragma unroll
      for (int r = 0; r < 4; ++r) {
        int loc = wm + mt * 16 + quad * 4 + r;        // row within tile
        int row = bm + loc;                           // C layout: row=(lane>>4)*4+reg
        float v = (acc[mt][nt][r] + bv) * sc;
        if (OUT_BF16)
          ((bf16_t*)Cout)[(size_t)row * Nn + col] = (bf16_t)v;
        else
          ((float*)Cout)[(size_t)row * Nn + col] = v;
        if (do_vt) {
          int dg = wn + nt * 16 + c;                  // col within tile [0,128)
          int hh = dg >> 6, dl = dg & 63;             // head-half, d within head
          tb[((loc & 1) * 2 + hh) * 4608 + dl * 72 + (loc >> 1)] = (bf16_t)v;
        }
      }
    }
  }

  if (do_vt) {
    __syncthreads();
    int h0 = (bn - 2 * HID) >> 6;        // first of the 2 heads in this tile
    constexpr int KV = 512 / TPB;        // vec-stores per thread per (i,hh)
    #pragma unroll
    for (int i = 0; i < 2; ++i) {        // batch b
      #pragma unroll
      for (int hh = 0; hh < 2; ++hh) {   // head within tile
        #pragma unroll
        for (int k = 0; k < KV; ++k) {
          int idx = k * TPB + tid;
          int d = idx >> 3;              // 0..63
          int n2 = (idx & 7) * 8;
          bf16x8 vv = *(const bf16x8*)(tb + ((i * 2 + hh) * 4608) + d * 72 + n2);
          *(bf16x8*)(Vt + (size_t)((i * 16 + h0 + hh) * HDIM + d) * N_SEQ + bm / 2 + n2) = vv;
        }
      }
    }
  }
}

// ---------------- flash attention: T15 two-tile pipeline (R9-verified) -----
__global__ __launch_bounds__(512, 4) void flash_attn_kernel(
    const bf16_t* __restrict__ Pj, const bf16_t* __restrict__ Vt,
    bf16_t* __restrict__ AO) {
  __shared__ __align__(16) bf16_t Ks[3][64 * 64];   // [j][d] swizzled
  __shared__ __align__(16) bf16_t Vs[3][64 * 64];   // [d][j] swizzled
  __shared__ __align__(16) bf16_t Ps[8][16 * 64];   // per-wave P[i][j] swizzled
  const int PJP = 3 * HID;
  int tid = threadIdx.x, wave = tid >> 6, lane = tid & 63;
  int c = lane & 15, quad = lane >> 4;
  int c7 = c & 7;
  int bid = blockIdx.x;
  int qb = (bid < 256) ? (15 - (bid >> 5)) : ((bid - 256) >> 5);
  int bh = bid & 31;
  int h = bh & 15, b = bh >> 4;
  int i0 = qb * 128;

  int i_row = i0 + wave * 16 + c;
  const bf16_t* qg = Pj + (size_t)(i_row * BATCH + b) * PJP + h * HDIM + quad * 8;
  bf16x8 qf0 = *(const bf16x8*)(qg);
  bf16x8 qf1 = *(const bf16x8*)(qg + 32);

  f32x4 o[4] = {};                   // O^T: rows d, col i=c
  float lrow = 0.f;

  int jr = tid >> 3, oc = tid & 7;
  int lds_off = jr * 64 + (oc ^ (jr & 7)) * 8;
  const bf16_t* kg0 = Pj + (size_t)b * PJP + HID + h * HDIM + oc * 8;
  const bf16_t* vg0 = Vt + (size_t)(bh * HDIM + jr) * N_SEQ + oc * 8;

  int njt = 2 * qb + 2;              // always >= 2

  // ---- prologue: stage tiles 0,1; QK(0); prefetch tile 2 ----
  bf16x8 kreg = *(const bf16x8*)(kg0 + (size_t)jr * BATCH * PJP);
  bf16x8 vreg = *(const bf16x8*)(vg0);
  *(bf16x8*)(Ks[0] + lds_off) = kreg;
  *(bf16x8*)(Vs[0] + lds_off) = vreg;
  kreg = *(const bf16x8*)(kg0 + (size_t)(64 + jr) * BATCH * PJP);
  vreg = *(const bf16x8*)(vg0 + 64);
  *(bf16x8*)(Ks[1] + lds_off) = kreg;
  *(bf16x8*)(Vs[1] + lds_off) = vreg;
  __syncthreads();                   // publish buffers 0 and 1

  f32x4 st[4];
  #pragma unroll
  for (int mt = 0; mt < 4; ++mt) {
    const bf16_t* kr = Ks[0] + (mt * 16 + c) * 64;
    bf16x8 ka0 = *(const bf16x8*)(kr + ((quad) ^ c7) * 8);
    bf16x8 ka1 = *(const bf16x8*)(kr + ((quad + 4) ^ c7) * 8);
    f32x4 s = {};
    s = __builtin_amdgcn_mfma_f32_16x16x32_bf16(ka0, qf0, s, 0, 0, 0);
    st[mt] = __builtin_amdgcn_mfma_f32_16x16x32_bf16(ka1, qf1, s, 0, 0, 0);
  }
  if (njt > 2) {
    kreg = *(const bf16x8*)(kg0 + (size_t)(128 + jr) * BATCH * PJP);
    vreg = *(const bf16x8*)(vg0 + 128);
  }

  for (int jt = 0; jt < njt; ++jt) {
    if (jt) __syncthreads();         // publish buf[(jt+1)%3]; WAR-guard buf[(jt+2)%3]
    if (jt + 2 < njt) {              // write tile jt+2 (regs loaded one iter ago)
      *(bf16x8*)(Ks[(jt + 2) % 3] + lds_off) = kreg;
      *(bf16x8*)(Vs[(jt + 2) % 3] + lds_off) = vreg;
    }
    if (jt + 3 < njt) {              // prefetch tile jt+3 into regs
      int j0n = (jt + 3) * 64;
      kreg = *(const bf16x8*)(kg0 + (size_t)(j0n + jr) * BATCH * PJP);
      vreg = *(const bf16x8*)(vg0 + j0n);
    }

    // QK(jt+1) issued BEFORE the exp of tile jt (independent -> interleave)
    f32x4 stN[4];
    bool more = (jt + 1 < njt);
    if (more) {
      const bf16_t* ks = Ks[(jt + 1) % 3];
      #pragma unroll
      for (int mt = 0; mt < 4; ++mt) {
        const bf16_t* kr = ks + (mt * 16 + c) * 64;
        bf16x8 ka0 = *(const bf16x8*)(kr + ((quad) ^ c7) * 8);
        bf16x8 ka1 = *(const bf16x8*)(kr + ((quad + 4) ^ c7) * 8);
        f32x4 s = {};
        s = __builtin_amdgcn_mfma_f32_16x16x32_bf16(ka0, qf0, s, 0, 0, 0);
        stN[mt] = __builtin_amdgcn_mfma_f32_16x16x32_bf16(ka1, qf1, s, 0, 0, 0);
      }
    }

    // ---- softmax finish of tile jt (VALU, overlaps QK above) ----
    if (jt >= 2 * qb) {
      int j0 = jt * 64;
      int ig = i0 + wave * 16 + c;
      #pragma unroll
      for (int mt = 0; mt < 4; ++mt)
        #pragma unroll
        for (int r = 0; r < 4; ++r)
          if (j0 + mt * 16 + quad * 4 + r > ig) st[mt][r] = -1e30f;
    }
    #pragma unroll
    for (int mt = 0; mt < 4; ++mt)
      #pragma unroll
      for (int r = 0; r < 4; ++r) {
        st[mt][r] = EXP2F(st[mt][r]);
        lrow += st[mt][r];
      }

    bf16_t* pw = Ps[wave];
    #pragma unroll
    for (int mt = 0; mt < 4; ++mt) {
      bf16x4 pv;
      #pragma unroll
      for (int r = 0; r < 4; ++r) pv[r] = (bf16_t)st[mt][r];
      int joct = mt * 2 + (quad >> 1);
      *(bf16x4*)(pw + c * 64 + (joct ^ c7) * 8 + (quad & 1) * 4) = pv;
    }
    const bf16_t* pr = pw + c * 64;
    bf16x8 pa0 = *(const bf16x8*)(pr + ((quad) ^ c7) * 8);
    bf16x8 pa1 = *(const bf16x8*)(pr + ((quad + 4) ^ c7) * 8);

    const bf16_t* vs = Vs[jt % 3];
    #pragma unroll
    for (int nt = 0; nt < 4; ++nt) {
      const bf16_t* vr = vs + (nt * 16 + c) * 64;
      bf16x8 vb0 = *(const bf16x8*)(vr + ((quad) ^ c7) * 8);
      bf16x8 vb1 = *(const bf16x8*)(vr + ((quad + 4) ^ c7) * 8);
      o[nt] = __builtin_amdgcn_mfma_f32_16x16x32_bf16(vb0, pa0, o[nt], 0, 0, 0);
      o[nt] = __builtin_amdgcn_mfma_f32_16x16x32_bf16(vb1, pa1, o[nt], 0, 0, 0);
    }

    if (more) {
      #pragma unroll
      for (int mt = 0; mt < 4; ++mt) st[mt] = stN[mt];
    }
  }

  float lfull = lrow;
  lfull += __shfl_xor(lfull, 16);
  lfull += __shfl_xor(lfull, 32);
  float linv = 1.0f / lfull;
  int orow = (i0 + wave * 16 + c) * BATCH + b;
  #pragma unroll
  for (int nt = 0; nt < 4; ++nt) {
    bf16x4 pv;
    #pragma unroll
    for (int r = 0; r < 4; ++r) pv[r] = (bf16_t)(o[nt][r] * linv);
    *(bf16x4*)(AO + (size_t)orow * HID + h * HDIM + nt * 16 + quad * 4) = pv;
  }
}

extern "C" void kernel_launch(void* const* d_in, const int* in_sizes, int n_in,
                              void* d_out, int out_size, void* d_ws, size_t ws_size,
                              hipStream_t stream) {
  const float* x      = (const float*)d_in[0];   // [2048][2][1024]
  const float* W_proj = (const float*)d_in[1];   // [1024][3072]
  const float* b_proj = (const float*)d_in[2];   // [3072]
  const float* W_out  = (const float*)d_in[3];   // [1024][1024]
  const float* b_out  = (const float*)d_in[4];   // [1024]

  bf16_t* Xb  = (bf16_t*)d_ws;                               // 4096*1024
  bf16_t* Wpt = Xb  + (size_t)NBROW * EMB;                   // 3072*1024
  bf16_t* Wot = Wpt + (size_t)3 * HID * EMB;                 // 1024*1024
  bf16_t* Pj  = Wot + (size_t)HID * EMB;                     // 4096*3072
  bf16_t* AO  = Pj  + (size_t)NBROW * 3 * HID;               // 4096*1024
  bf16_t* Vt  = AO  + (size_t)NBROW * HID;                   // 32*64*2048

  prep_kernel<<<8192, 256, 0, stream>>>(x, W_proj, W_out, Xb, Wpt, Wot);
  // QKV: 512-thread blocks -> 16 waves/CU (2 blk/CU), tail round at 8 waves/CU
  gemm_bt_kernel<128, 128, 512, true, true, true>
      <<<dim3(NBROW / 128, 3 * HID / 128), 512, 0, stream>>>(
      Xb, Wpt, b_proj, (void*)Pj, Vt, NBROW, 3 * HID, EMB);
  flash_attn_kernel<<<512, 512, 0, stream>>>(Pj, Vt, AO);
  // out-projection: BN=64, 256 threads (R10-verified)
  gemm_bt_kernel<128, 64, 256, false, false, false>
      <<<dim3(NBROW / 128, EMB / 64), 256, 0, stream>>>(
      AO, Wot, b_out, d_out, nullptr, NBROW, EMB, HID);
}